// Round 10
// baseline (560.331 us; speedup 1.0000x reference)
//
#include <hip/hip_runtime.h>

// LSTMModel: 4-layer LSTM (H=50, IN=7, B=1024, T=512) + FC(50->25 relu ->1).
// R10 = R8 + register-lean phase stagger (R9 retried without the spill).
// Two barriered windows per iteration:
//   W1: even layers (0,2) MFMA+select -> ga ; odd layers (1,3) update from ga
//   W2: even layers update ; odd layers MFMA+select -> ga
// Only ga (4 VGPRs) persists across a barrier; acc a0..a3 die inside M_PHASE.
// Exactly 6 LDS pointers per wave (mi/mo/us x 2 iteration parities).
// Schedule (iteration i, ip=i&1), all producer->consumer >=1 barrier apart,
// no same-window LDS overlap (verified per-buffer):
//   L0: M(t=i)@W1 reads Xpack[ip] (x(t)|1|h0(t-1)); U@W2 writes Xpack[ip^1]
//   L1: M(t=i-1)@W2 reads Xpack[ip], Hbuf0[ip]; U(t=i-2)@W1 writes Hbuf0[ip]
//   L2: M(t=i-3)@W1 reads Hbuf0[ip^1], Hbuf1[ip]; U@W2 writes Hbuf1[ip^1]
//   L3: M(t=i-4)@W2 reads Hbuf1[ip], Hbuf2[ip^1]; U(t=i-5)@W1 writes Hbuf2[ip^1]
// xcopy (x(i+1) ring->Xpack[ip^1]) in W2; x-slots read by L1 multiply A=0.
// Iterations 0..516; prologue 0..4, steady 5..510 (x2 unroll), tail 511..516.

#define H 50
#define INSZ 7
#define TT 512
#define NL 4
#define FC1N 25
#define BPG 4
#define NBLK 256
#define NTHREADS 1024
#define HS 80        // row stride in halves (40 dw = 8 mod 32: <=2-way, free)
#define BIASL 56

typedef _Float16 half_t;
typedef __attribute__((ext_vector_type(8))) _Float16 half8_t;
typedef __attribute__((ext_vector_type(4))) float float4_t;

struct Params {
  const float* x;
  const float* Wih[NL];
  const float* Whh[NL];
  const float* bih[NL];
  const float* bhh[NL];
  const float* W1;
  const float* b1;
  const float* W2;
  const float* b2;
  float* out;
};

#define MFMA16(A, B, C) __builtin_amdgcn_mfma_f32_16x16x32_f16((A), (B), (C), 0, 0, 0)
#define EXP2F(x) __builtin_amdgcn_exp2f(x)
#define RCPF(x) __builtin_amdgcn_rcpf(x)

__global__ __launch_bounds__(NTHREADS, 4) void lstm_r10(Params p) {
  __shared__ __align__(16) half_t Xpack[2][BPG][HS];     // L0 B-row / L1 input
  __shared__ __align__(16) half_t Hbuf[3][2][BPG][HS];   // own-h L1..L3
  __shared__ __align__(16) half_t Xstage[64][BPG][8];    // raw-x ring
  __shared__ float fc_h[BPG][H];
  __shared__ float fc1_buf[BPG][FC1N];

  const int tid = threadIdx.x;
  const int b0 = blockIdx.x * BPG;
  const int lane = tid & 63;
  const int quad = lane >> 4;
  const int col = lane & 15;
  const int glay = tid >> 8;                     // layer (4 waves each)
  const int wl = (((tid >> 6) & 3) + glay) & 3;  // M-chunk, SIMD-balanced
  const bool evl = (glay & 1) == 0;

  // ---- A fragments (identical maps to R8) ----
  half8_t afrag[4][4];
#pragma unroll
  for (int t4 = 0; t4 < 4; ++t4) {
#pragma unroll
    for (int g = 0; g < 4; ++g) {
      half8_t v;
#pragma unroll
      for (int j = 0; j < 8; ++j) {
        const int r = wl * 64 + t4 * 16 + col;
        const int u = r >> 2, q = r & 3;
        const int k = g * 32 + quad * 8 + j;
        float wv = 0.0f;
        if (u < H) {
          const int row = q * H + u;
          if (glay == 0) {           // K=64: x 0..6, bias 7, own-h 8..57
            if (k < INSZ) wv = p.Wih[0][row * INSZ + k];
            else if (k == 7) wv = p.bih[0][row] + p.bhh[0][row];
            else if (k >= 8 && k < 8 + H) wv = p.Whh[0][row * H + (k - 8)];
          } else if (glay == 1) {    // input from Xpack: bias 7, in-h 8..57
            if (k == 7) wv = p.bih[1][row] + p.bhh[1][row];
            else if (k >= 8 && k < 8 + H) wv = p.Wih[1][row * H + (k - 8)];
            else if (k >= 64 && k < 64 + H) wv = p.Whh[1][row * H + (k - 64)];
          } else {                   // in-h 0..49, bias 56, own-h 64..113
            if (k < H) wv = p.Wih[glay][row * H + k];
            else if (k == BIASL) wv = p.bih[glay][row] + p.bhh[glay][row];
            else if (k >= 64 && k < 64 + H) wv = p.Whh[glay][row * H + (k - 64)];
          }
        }
        v[j] = (half_t)wv;
      }
      afrag[t4][g] = v;
    }
  }

  // ---- init LDS ----
  {
    unsigned* xz = (unsigned*)Xpack;
    for (int i = tid; i < 2 * BPG * HS / 2; i += NTHREADS) xz[i] = 0u;
    unsigned* hz = (unsigned*)Hbuf;
    for (int i = tid; i < 3 * 2 * BPG * HS / 2; i += NTHREADS) hz[i] = 0u;
  }
  __syncthreads();
  if (tid < 8) {  // Xpack bias-1.0 at slot 7, both parities
    Xpack[tid >> 2][tid & 3][7] = (half_t)1.0f;
  } else if (tid < 8 + 24) {  // Hbuf const-1.0 at slot 56
    const int i = tid - 8, l = i >> 3, pr = (i >> 2) & 1, b = i & 3;
    Hbuf[l][pr][b][BIASL] = (half_t)1.0f;
  }
  // ring fill t=0..63; x(0) -> Xpack[0]
  for (int i = tid; i < 64 * BPG * INSZ; i += NTHREADS) {
    const int t = i / (BPG * INSZ), rem = i % (BPG * INSZ);
    const int b = rem / INSZ, k = rem % INSZ;
    const half_t xh = (half_t)p.x[((size_t)(b0 + b) * TT + t) * INSZ + k];
    Xstage[t][b][k] = xh;
    if (t == 0) Xpack[0][b][k] = xh;
  }
  __syncthreads();

  // ---- per-lane roles ----
  const int bb = col & 3;
  const int tsel = col >> 2;
  const int uu = 16 * wl + 4 * tsel + quad;
  const bool updact = (uu < H);

  // 6 pointers per wave, indexed by iteration parity ip = i&1
  const half_t* mi2[2];
  const half_t* mo2[2];
  half_t* us2[2];
  if (glay == 0) {
    mi2[0] = &Xpack[0][bb][quad * 8];
    mi2[1] = &Xpack[1][bb][quad * 8];
    mo2[0] = mi2[0];
    mo2[1] = mi2[1];
    us2[0] = &Xpack[1][bb][8 + uu];
    us2[1] = &Xpack[0][bb][8 + uu];
  } else if (glay == 1) {
    mi2[0] = &Xpack[0][bb][quad * 8];
    mi2[1] = &Xpack[1][bb][quad * 8];
    mo2[0] = &Hbuf[0][0][bb][quad * 8];
    mo2[1] = &Hbuf[0][1][bb][quad * 8];
    us2[0] = &Hbuf[0][0][bb][uu];
    us2[1] = &Hbuf[0][1][bb][uu];
  } else if (glay == 2) {
    mi2[0] = &Hbuf[0][1][bb][quad * 8];
    mi2[1] = &Hbuf[0][0][bb][quad * 8];
    mo2[0] = &Hbuf[1][0][bb][quad * 8];
    mo2[1] = &Hbuf[1][1][bb][quad * 8];
    us2[0] = &Hbuf[1][1][bb][uu];
    us2[1] = &Hbuf[1][0][bb][uu];
  } else {
    mi2[0] = &Hbuf[1][0][bb][quad * 8];
    mi2[1] = &Hbuf[1][1][bb][quad * 8];
    mo2[0] = &Hbuf[2][1][bb][quad * 8];
    mo2[1] = &Hbuf[2][0][bb][quad * 8];
    us2[0] = &Hbuf[2][1][bb][uu];
    us2[1] = &Hbuf[2][0][bb][uu];
  }

  // x-copy + ring-refill role: layer-0 wl==3 wave (lightest)
  const bool xwave = (glay == 0) && (wl == 3);
  const bool xcopy = xwave && (lane < BPG * INSZ);
  const int cb = lane / INSZ, ck = lane % INSZ;
  const int rb = lane >> 5;
  const int rt = lane & 31;

  float cst = 0.0f;
  float4_t ga;  // selected gates; persists across ONE barrier only
  {
    const float4_t z = {0.0f, 0.0f, 0.0f, 0.0f};
    ga = z;
  }

  // M phase: MFMA + 3-level select into ga (acc dies here)
#define M_PHASE(PIN, POWN)                                                      \
  {                                                                             \
    const float4_t fzc = {0.0f, 0.0f, 0.0f, 0.0f};                              \
    float4_t a0 = fzc, a1 = fzc, a2 = fzc, a3 = fzc;                            \
    if (glay == 0) {                                                            \
      const half8_t v0 = *(const half8_t*)(POWN);                               \
      const half8_t v1 = *(const half8_t*)((POWN) + 32);                        \
      if (wl != 3) {                                                            \
        a0 = MFMA16(afrag[0][0], v0, a0); a1 = MFMA16(afrag[1][0], v0, a1);     \
        a2 = MFMA16(afrag[2][0], v0, a2); a3 = MFMA16(afrag[3][0], v0, a3);     \
        a0 = MFMA16(afrag[0][1], v1, a0); a1 = MFMA16(afrag[1][1], v1, a1);     \
        a2 = MFMA16(afrag[2][1], v1, a2); a3 = MFMA16(afrag[3][1], v1, a3);     \
      } else {                                                                  \
        a0 = MFMA16(afrag[0][0], v0, a0);                                       \
        a0 = MFMA16(afrag[0][1], v1, a0);                                       \
      }                                                                         \
    } else {                                                                    \
      const half8_t v0 = *(const half8_t*)(PIN);                                \
      const half8_t v1 = *(const half8_t*)((PIN) + 32);                         \
      const half8_t v2 = *(const half8_t*)(POWN);                               \
      const half8_t v3 = *(const half8_t*)((POWN) + 32);                        \
      if (wl != 3) {                                                            \
        a0 = MFMA16(afrag[0][0], v0, a0); a1 = MFMA16(afrag[1][0], v0, a1);     \
        a2 = MFMA16(afrag[2][0], v0, a2); a3 = MFMA16(afrag[3][0], v0, a3);     \
        a0 = MFMA16(afrag[0][1], v1, a0); a1 = MFMA16(afrag[1][1], v1, a1);     \
        a2 = MFMA16(afrag[2][1], v1, a2); a3 = MFMA16(afrag[3][1], v1, a3);     \
        a0 = MFMA16(afrag[0][2], v2, a0); a1 = MFMA16(afrag[1][2], v2, a1);     \
        a2 = MFMA16(afrag[2][2], v2, a2); a3 = MFMA16(afrag[3][2], v2, a3);     \
        a0 = MFMA16(afrag[0][3], v3, a0); a1 = MFMA16(afrag[1][3], v3, a1);     \
        a2 = MFMA16(afrag[2][3], v3, a2); a3 = MFMA16(afrag[3][3], v3, a3);     \
      } else {                                                                  \
        a0 = MFMA16(afrag[0][0], v0, a0);                                       \
        a0 = MFMA16(afrag[0][1], v1, a0);                                       \
        a0 = MFMA16(afrag[0][2], v2, a0);                                       \
        a0 = MFMA16(afrag[0][3], v3, a0);                                       \
      }                                                                         \
    }                                                                           \
    const float4_t g01 = (col & 4) ? a1 : a0;                                   \
    const float4_t g23 = (col & 4) ? a3 : a2;                                   \
    ga = (col & 8) ? g23 : g01;                                                 \
  }

#define U_PHASE(PST, FCW)                                                       \
  if (updact) {                                                                 \
    const float di = 1.0f + EXP2F(-1.442695041f * ga[0]);                       \
    const float df = 1.0f + EXP2F(-1.442695041f * ga[1]);                       \
    const float dg = 1.0f + EXP2F(-2.885390082f * ga[2]);                       \
    const float dq = 1.0f + EXP2F(-1.442695041f * ga[3]);                       \
    const float r1 = RCPF(di * df);                                             \
    const float r2 = RCPF(dg * dq);                                             \
    const float gi = r1 * df;                                                   \
    const float gf = r1 * di;                                                   \
    const float gg = 2.0f * (r2 * dq) - 1.0f;                                   \
    const float go = r2 * dg;                                                   \
    cst = gf * cst + gi * gg;                                                   \
    const float dc = 1.0f + EXP2F(-2.885390082f * cst);                         \
    const float h = go * (2.0f * RCPF(dc) - 1.0f);                              \
    *(PST) = (half_t)h;                                                         \
    if (FCW) fc_h[bb][uu] = h;                                                  \
  }

  // ---- prologue: i = 0..4 (fully unrolled -> compile-time parity) ----
#pragma unroll
  for (int i = 0; i < 5; ++i) {
    const int ip = i & 1;
    // W1: even M | odd U
    if (evl) {
      if (i >= ((glay == 0) ? 0 : 3)) M_PHASE(mi2[ip], mo2[ip])
    } else {
      if (i >= ((glay == 1) ? 2 : 5)) U_PHASE(us2[ip], false)
    }
    __syncthreads();
    // W2: even U (+xcopy) | odd M
    if (evl) {
      if (i >= ((glay == 0) ? 0 : 3)) U_PHASE(us2[ip], false)
      if (xcopy) Xpack[(i + 1) & 1][cb][ck] = Xstage[(i + 1) & 63][cb][ck];
    } else {
      if (i >= ((glay == 1) ? 1 : 4)) M_PHASE(mi2[ip], mo2[ip])
    }
    __syncthreads();
  }

  // hoisted steady pointers
  const half_t* mi_o = mi2[1];
  const half_t* mo_o = mo2[1];
  half_t* us_o = us2[1];
  const half_t* mi_e = mi2[0];
  const half_t* mo_e = mo2[0];
  half_t* us_e = us2[0];

  // ---- steady: i = 5..510, unrolled x2 (odd i then even i+1) ----
  for (int i = 5; i < 511; i += 2) {
    // iteration i (ip=1)
    if (evl) M_PHASE(mi_o, mo_o)
    else U_PHASE(us_o, false)
    __syncthreads();
    if (evl) {
      U_PHASE(us_o, false)
      if (xcopy) Xpack[i & 1 ^ 1][cb][ck] = Xstage[(i + 1) & 63][cb][ck];
    } else {
      M_PHASE(mi_o, mo_o)
    }
    __syncthreads();
    // iteration i+1 (ip=0)
    if (evl) M_PHASE(mi_e, mo_e)
    else U_PHASE(us_e, false)
    __syncthreads();
    if (evl) {
      if (xwave && ((i + 1) & 31) == 8 && (i + 1) < 480) {  // ring refill burst
        const int tb = ((i + 1) & ~31) + 32;
#pragma unroll
        for (int pp = 0; pp < 2; ++pp) {
          const int b = rb + 2 * pp;
          const int t = tb + rt;
          const float* src = &p.x[((size_t)(b0 + b) * TT + t) * INSZ];
          half_t* dst = &Xstage[t & 63][b][0];
#pragma unroll
          for (int k = 0; k < INSZ; ++k) dst[k] = (half_t)src[k];
        }
      }
      U_PHASE(us_e, false)
      if (xcopy) Xpack[(i + 2) & 1][cb][ck] = Xstage[(i + 2) & 63][cb][ck];
    } else {
      M_PHASE(mi_e, mo_e)
    }
    __syncthreads();
  }

  // ---- tail: i = 511..516 (unrolled, guarded; no xcopy) ----
#pragma unroll
  for (int i = 511; i < 517; ++i) {
    const int ip = i & 1;
    if (evl) {
      if (i <= ((glay == 0) ? 511 : 514)) M_PHASE(mi2[ip], mo2[ip])
    } else {
      if (i <= ((glay == 1) ? 513 : 516))
        U_PHASE(us2[ip], (glay == 3) && (i == 516))
    }
    __syncthreads();
    if (evl) {
      if (i <= ((glay == 0) ? 511 : 514)) U_PHASE(us2[ip], false)
    } else {
      if (i <= ((glay == 1) ? 512 : 515)) M_PHASE(mi2[ip], mo2[ip])
    }
    __syncthreads();
  }

  // ---- FC head (fp32) ----
  if (tid < BPG * FC1N) {
    const int b = tid / FC1N, j = tid % FC1N;
    const float* w = p.W1 + j * H;
    float a = p.b1[j];
#pragma unroll
    for (int k = 0; k < H; ++k) a += fc_h[b][k] * w[k];
    fc1_buf[b][j] = fmaxf(a, 0.0f);
  }
  __syncthreads();
  if (tid < BPG) {
    float a = p.b2[0];
#pragma unroll
    for (int j = 0; j < FC1N; ++j) a += fc1_buf[tid][j] * p.W2[j];
    p.out[b0 + tid] = a;
  }
}

extern "C" void kernel_launch(void* const* d_in, const int* in_sizes, int n_in,
                              void* d_out, int out_size, void* d_ws, size_t ws_size,
                              hipStream_t stream) {
  Params p;
  p.x = (const float*)d_in[0];
  for (int l = 0; l < NL; ++l) {
    p.Wih[l] = (const float*)d_in[1 + 4 * l];
    p.Whh[l] = (const float*)d_in[2 + 4 * l];
    p.bih[l] = (const float*)d_in[3 + 4 * l];
    p.bhh[l] = (const float*)d_in[4 + 4 * l];
  }
  p.W1 = (const float*)d_in[17];
  p.b1 = (const float*)d_in[18];
  p.W2 = (const float*)d_in[19];
  p.b2 = (const float*)d_in[20];
  p.out = (float*)d_out;

  hipLaunchKernelGGL(lstm_r10, dim3(NBLK), dim3(NTHREADS), 0, stream, p);
}

// Round 11
// 475.107 us; speedup vs baseline: 1.1794x; 1.1794x over previous
//
#include <hip/hip_runtime.h>

// LSTMModel: 4-layer LSTM (H=50, IN=7, B=1024, T=512) + FC(50->25 relu ->1).
// R11 = R8 (best, 475us) + issue shaving; R9/R10 taught that extra barriers
// (phase stagger) cost more than pipe overlap gains, so single barrier/tick.
//  - A-fragments pre-scaled by -log2(e) (i,f,o rows) / -2*log2(e) (g rows):
//    MFMA delivers exp2-ready arguments; U-phase loses 4 muls+negates/cell.
//  - xcopy/refill issue BEFORE the MFMA body in the window.
//  - explicit fmaf in the update tail.
// Layout (R8): Xpack[2][4][80] row = [x(t) 0..6 | 1.0 at 7 | h0(t-1) 8..57];
// L0 reads 2xb128 (K=64, 8 MFMAs); L1 reads the same row as input. Hbuf[3]
// for h1..h3 (bias-1.0 at 56). Xstage raw-x ring, burst-refilled. One h-store
// per update lane; broadcast B-reads; row stride 80 halves (<=2-way banks).

#define H 50
#define INSZ 7
#define TT 512
#define NL 4
#define FC1N 25
#define BPG 4
#define NBLK 256
#define NTHREADS 1024
#define HS 80        // row stride in halves (40 dw = 8 mod 32: <=2-way, free)
#define BIASL 56

typedef _Float16 half_t;
typedef __attribute__((ext_vector_type(8))) _Float16 half8_t;
typedef __attribute__((ext_vector_type(4))) float float4_t;

struct Params {
  const float* x;
  const float* Wih[NL];
  const float* Whh[NL];
  const float* bih[NL];
  const float* bhh[NL];
  const float* W1;
  const float* b1;
  const float* W2;
  const float* b2;
  float* out;
};

#define MFMA16(A, B, C) __builtin_amdgcn_mfma_f32_16x16x32_f16((A), (B), (C), 0, 0, 0)
#define EXP2F(x) __builtin_amdgcn_exp2f(x)
#define RCPF(x) __builtin_amdgcn_rcpf(x)
#define NL2E (-1.442695041f)    // -log2(e)
#define N2L2E (-2.885390082f)   // -2*log2(e)

__global__ __launch_bounds__(NTHREADS, 4) void lstm_r11(Params p) {
  __shared__ __align__(16) half_t Xpack[2][BPG][HS];     // L0 B-row / L1 input
  __shared__ __align__(16) half_t Hbuf[3][2][BPG][HS];   // own-h L1..L3
  __shared__ __align__(16) half_t Xstage[64][BPG][8];    // raw-x ring
  __shared__ float fc_h[BPG][H];
  __shared__ float fc1_buf[BPG][FC1N];

  const int tid = threadIdx.x;
  const int b0 = blockIdx.x * BPG;
  const int lane = tid & 63;
  const int quad = lane >> 4;
  const int col = lane & 15;
  const int glay = tid >> 8;                     // layer (4 waves each)
  const int wl = (((tid >> 6) & 3) + glay) & 3;  // M-chunk, SIMD-balanced

  // ---- A fragments (R8 maps) with exp2-argument scale folded in ----
  // row r = wl*64 + t4*16 + col (unit-major r=4u+q), k = g*32 + quad*8 + j.
  // q==2 (cell gate) scaled by -2*log2e, else -log2e. Bias scaled likewise.
  half8_t afrag[4][4];
#pragma unroll
  for (int t4 = 0; t4 < 4; ++t4) {
#pragma unroll
    for (int g = 0; g < 4; ++g) {
      half8_t v;
#pragma unroll
      for (int j = 0; j < 8; ++j) {
        const int r = wl * 64 + t4 * 16 + col;
        const int u = r >> 2, q = r & 3;
        const int k = g * 32 + quad * 8 + j;
        float wv = 0.0f;
        if (u < H) {
          const int row = q * H + u;
          if (glay == 0) {           // K=64: x 0..6, bias 7, own-h 8..57
            if (k < INSZ) wv = p.Wih[0][row * INSZ + k];
            else if (k == 7) wv = p.bih[0][row] + p.bhh[0][row];
            else if (k >= 8 && k < 8 + H) wv = p.Whh[0][row * H + (k - 8)];
          } else if (glay == 1) {    // input from Xpack: bias 7, in-h 8..57
            if (k == 7) wv = p.bih[1][row] + p.bhh[1][row];
            else if (k >= 8 && k < 8 + H) wv = p.Wih[1][row * H + (k - 8)];
            else if (k >= 64 && k < 64 + H) wv = p.Whh[1][row * H + (k - 64)];
          } else {                   // in-h 0..49, bias 56, own-h 64..113
            if (k < H) wv = p.Wih[glay][row * H + k];
            else if (k == BIASL) wv = p.bih[glay][row] + p.bhh[glay][row];
            else if (k >= 64 && k < 64 + H) wv = p.Whh[glay][row * H + (k - 64)];
          }
          wv *= (q == 2) ? N2L2E : NL2E;  // fold exp2 scale+negate into A
        }
        v[j] = (half_t)wv;
      }
      afrag[t4][g] = v;
    }
  }

  // ---- init LDS ----
  {
    unsigned* xz = (unsigned*)Xpack;
    for (int i = tid; i < 2 * BPG * HS / 2; i += NTHREADS) xz[i] = 0u;
    unsigned* hz = (unsigned*)Hbuf;
    for (int i = tid; i < 3 * 2 * BPG * HS / 2; i += NTHREADS) hz[i] = 0u;
  }
  __syncthreads();
  if (tid < 8) {  // Xpack bias-1.0 at slot 7, both parities
    Xpack[tid >> 2][tid & 3][7] = (half_t)1.0f;
  } else if (tid < 8 + 24) {  // Hbuf const-1.0 at slot 56
    const int i = tid - 8, l = i >> 3, pr = (i >> 2) & 1, b = i & 3;
    Hbuf[l][pr][b][BIASL] = (half_t)1.0f;
  }
  // ring fill t=0..63 + x(0) into Xpack[0]
  for (int i = tid; i < 64 * BPG * INSZ; i += NTHREADS) {
    const int t = i / (BPG * INSZ), rem = i % (BPG * INSZ);
    const int b = rem / INSZ, k = rem % INSZ;
    const half_t xh = (half_t)p.x[((size_t)(b0 + b) * TT + t) * INSZ + k];
    Xstage[t][b][k] = xh;
    if (t == 0) Xpack[0][b][k] = xh;
  }
  __syncthreads();

  // ---- per-lane roles ----
  const int bb = col & 3;
  const int tsel = col >> 2;
  const int uu = 16 * wl + 4 * tsel + quad;
  const bool updact = (uu < H);

  // phase-hoisted pointers: read [s&1], store [(s+1)&1].
  const half_t* pin2[2];
  const half_t* pown2[2];
  half_t* pst2[2];
  if (glay == 0) {
    pin2[0] = &Xpack[0][bb][quad * 8];
    pin2[1] = &Xpack[1][bb][quad * 8];
    pown2[0] = pin2[0];  // unused
    pown2[1] = pin2[1];
    pst2[0] = &Xpack[1][bb][8 + uu];
    pst2[1] = &Xpack[0][bb][8 + uu];
  } else if (glay == 1) {
    pin2[0] = &Xpack[0][bb][quad * 8];
    pin2[1] = &Xpack[1][bb][quad * 8];
    pown2[0] = &Hbuf[0][0][bb][quad * 8];
    pown2[1] = &Hbuf[0][1][bb][quad * 8];
    pst2[0] = &Hbuf[0][1][bb][uu];
    pst2[1] = &Hbuf[0][0][bb][uu];
  } else {
    pin2[0] = &Hbuf[glay - 2][0][bb][quad * 8];
    pin2[1] = &Hbuf[glay - 2][1][bb][quad * 8];
    pown2[0] = &Hbuf[glay - 1][0][bb][quad * 8];
    pown2[1] = &Hbuf[glay - 1][1][bb][quad * 8];
    pst2[0] = &Hbuf[glay - 1][1][bb][uu];
    pst2[1] = &Hbuf[glay - 1][0][bb][uu];
  }
  const half_t* in_e = pin2[0];
  const half_t* in_o = pin2[1];
  const half_t* own_e = pown2[0];
  const half_t* own_o = pown2[1];
  half_t* st_e = pst2[0];
  half_t* st_o = pst2[1];

  // x-copy + ring-refill role: layer-0 wl==3 wave (lightest: 2 MFMAs)
  const bool xwave = (glay == 0) && (wl == 3);
  const bool xcopy = xwave && (lane < BPG * INSZ);
  const int cb = lane / INSZ, ck = lane % INSZ;
  const int rb = lane >> 5;
  const int rt = lane & 31;

  float cst = 0.0f;
  const float4_t fzc = {0.0f, 0.0f, 0.0f, 0.0f};

#define TICK_BODY(PIN, POWN, PST, FCW)                                          \
  {                                                                             \
    float4_t a0 = fzc, a1 = fzc, a2 = fzc, a3 = fzc;                            \
    if (glay == 0) {                                                            \
      const half8_t v0 = *(const half8_t*)(PIN);                                \
      const half8_t v1 = *(const half8_t*)((PIN) + 32);                         \
      if (wl != 3) {                                                            \
        a0 = MFMA16(afrag[0][0], v0, a0); a1 = MFMA16(afrag[1][0], v0, a1);     \
        a2 = MFMA16(afrag[2][0], v0, a2); a3 = MFMA16(afrag[3][0], v0, a3);     \
        a0 = MFMA16(afrag[0][1], v1, a0); a1 = MFMA16(afrag[1][1], v1, a1);     \
        a2 = MFMA16(afrag[2][1], v1, a2); a3 = MFMA16(afrag[3][1], v1, a3);     \
      } else {                                                                  \
        a0 = MFMA16(afrag[0][0], v0, a0);                                       \
        a0 = MFMA16(afrag[0][1], v1, a0);                                       \
      }                                                                         \
    } else {                                                                    \
      const half8_t v0 = *(const half8_t*)(PIN);                                \
      const half8_t v1 = *(const half8_t*)((PIN) + 32);                         \
      const half8_t v2 = *(const half8_t*)(POWN);                               \
      const half8_t v3 = *(const half8_t*)((POWN) + 32);                        \
      if (wl != 3) {                                                            \
        a0 = MFMA16(afrag[0][0], v0, a0); a1 = MFMA16(afrag[1][0], v0, a1);     \
        a2 = MFMA16(afrag[2][0], v0, a2); a3 = MFMA16(afrag[3][0], v0, a3);     \
        a0 = MFMA16(afrag[0][1], v1, a0); a1 = MFMA16(afrag[1][1], v1, a1);     \
        a2 = MFMA16(afrag[2][1], v1, a2); a3 = MFMA16(afrag[3][1], v1, a3);     \
        a0 = MFMA16(afrag[0][2], v2, a0); a1 = MFMA16(afrag[1][2], v2, a1);     \
        a2 = MFMA16(afrag[2][2], v2, a2); a3 = MFMA16(afrag[3][2], v2, a3);     \
        a0 = MFMA16(afrag[0][3], v3, a0); a1 = MFMA16(afrag[1][3], v3, a1);     \
        a2 = MFMA16(afrag[2][3], v3, a2); a3 = MFMA16(afrag[3][3], v3, a3);     \
      } else {                                                                  \
        a0 = MFMA16(afrag[0][0], v0, a0);                                       \
        a0 = MFMA16(afrag[0][1], v1, a0);                                       \
        a0 = MFMA16(afrag[0][2], v2, a0);                                       \
        a0 = MFMA16(afrag[0][3], v3, a0);                                       \
      }                                                                         \
    }                                                                           \
    if (updact) {                                                               \
      const float4_t g01 = (col & 4) ? a1 : a0;                                 \
      const float4_t g23 = (col & 4) ? a3 : a2;                                 \
      const float4_t ga = (col & 8) ? g23 : g01;                                \
      const float di = 1.0f + EXP2F(ga[0]);                                     \
      const float df = 1.0f + EXP2F(ga[1]);                                     \
      const float dg = 1.0f + EXP2F(ga[2]);                                     \
      const float dq = 1.0f + EXP2F(ga[3]);                                     \
      const float r1 = RCPF(di * df);                                           \
      const float r2 = RCPF(dg * dq);                                           \
      const float gi = r1 * df;                                                 \
      const float gf = r1 * di;                                                 \
      const float gg = fmaf(2.0f, r2 * dq, -1.0f);                              \
      const float go = r2 * dg;                                                 \
      cst = fmaf(gf, cst, gi * gg);                                             \
      const float dc = 1.0f + EXP2F(N2L2E * cst);                               \
      const float h = go * fmaf(2.0f, RCPF(dc), -1.0f);                         \
      *(PST) = (half_t)h;                                                       \
      if (FCW) fc_h[bb][uu] = h;                                                \
    }                                                                           \
  }

  // x-copy: ring row (s+1) -> Xpack[(s+1)&1] slots 0..6 (one light wave)
#define XCOPY(S)                                                                \
  if (xcopy) {                                                                  \
    const int tn = (S) + 1;                                                     \
    Xpack[tn & 1][cb][ck] = Xstage[tn & 63][cb][ck];                            \
  }

  // ---- prologue: s = 0..2 (guarded, dynamic parity) ----
  for (int s = 0; s < 3; ++s) {
    const int t = s - glay;
    XCOPY(s)
    if (t >= 0) {
      const int ph = s & 1;
      TICK_BODY(pin2[ph], pown2[ph], pst2[ph], false)
    }
    __syncthreads();
  }

  // ---- steady: s = 3..510, unrolled x2, compile-time phase ----
  for (int s = 3; s < 511; s += 2) {
    {  // odd tick s (ph=1)
      XCOPY(s)
      TICK_BODY(in_o, own_o, st_o, false)
    }
    __syncthreads();
    {  // even tick s+1 (ph=0)
      const int s2 = s + 1;
      if (xwave && (s2 & 31) == 8 && s2 < 480) {  // ring refill burst
        const int tb = (s2 & ~31) + 32;
#pragma unroll
        for (int pp = 0; pp < 2; ++pp) {
          const int b = rb + 2 * pp;
          const int t = tb + rt;
          const float* src = &p.x[((size_t)(b0 + b) * TT + t) * INSZ];
          half_t* dst = &Xstage[t & 63][b][0];
#pragma unroll
          for (int k = 0; k < INSZ; ++k) dst[k] = (half_t)src[k];
        }
      }
      XCOPY(s2)
      TICK_BODY(in_e, own_e, st_e, false)
    }
    __syncthreads();
  }

  // ---- tail: s = 511..514 (guarded; no x-copy) ----
  for (int s = 511; s < TT + NL - 1; ++s) {
    const int t = s - glay;
    if (t < TT) {
      const int ph = s & 1;
      const bool fcw = (glay == NL - 1) && (t == TT - 1);
      TICK_BODY(pin2[ph], pown2[ph], pst2[ph], fcw)
    }
    __syncthreads();
  }

  // ---- FC head (fp32) ----
  if (tid < BPG * FC1N) {
    const int b = tid / FC1N, j = tid % FC1N;
    const float* w = p.W1 + j * H;
    float a = p.b1[j];
#pragma unroll
    for (int k = 0; k < H; ++k) a += fc_h[b][k] * w[k];
    fc1_buf[b][j] = fmaxf(a, 0.0f);
  }
  __syncthreads();
  if (tid < BPG) {
    float a = p.b2[0];
#pragma unroll
    for (int j = 0; j < FC1N; ++j) a += fc1_buf[tid][j] * p.W2[j];
    p.out[b0 + tid] = a;
  }
}

extern "C" void kernel_launch(void* const* d_in, const int* in_sizes, int n_in,
                              void* d_out, int out_size, void* d_ws, size_t ws_size,
                              hipStream_t stream) {
  Params p;
  p.x = (const float*)d_in[0];
  for (int l = 0; l < NL; ++l) {
    p.Wih[l] = (const float*)d_in[1 + 4 * l];
    p.Whh[l] = (const float*)d_in[2 + 4 * l];
    p.bih[l] = (const float*)d_in[3 + 4 * l];
    p.bhh[l] = (const float*)d_in[4 + 4 * l];
  }
  p.W1 = (const float*)d_in[17];
  p.b1 = (const float*)d_in[18];
  p.W2 = (const float*)d_in[19];
  p.b2 = (const float*)d_in[20];
  p.out = (float*)d_out;

  hipLaunchKernelGGL(lstm_r11, dim3(NBLK), dim3(NTHREADS), 0, stream, p);
}